// Round 2
// baseline (25823.560 us; speedup 1.0000x reference)
//
#include <hip/hip_runtime.h>
#include <cstdint>

#define T_STEPS 8192
#define HDIM    1024
#define NBLK    128
#define NTHR    512

typedef unsigned int u32x4 __attribute__((ext_vector_type(4)));

__device__ __forceinline__ float dot4(float4 a, float4 b) {
    return a.x * b.x + a.y * b.y + a.z * b.z + a.w * b.w;
}
__device__ __forceinline__ float sigmoidf_(float v) { return 1.0f / (1.0f + __expf(-v)); }
__device__ __forceinline__ float tanhf_(float v)    { return 1.0f - 2.0f / (__expf(2.0f * v) + 1.0f); }

// One poll = ONE coherent 16B load (2 ring slots) + ONE waitcnt, fused in a
// single asm block so the output regs are valid at asm end (rule-#18 safe).
// sc0 sc1 => system-scope load, bypasses the (non-XCD-coherent) L2.
__device__ __forceinline__ u32x4 poll2(unsigned long long a) {
    u32x4 r;
    asm volatile("global_load_dwordx4 %0, %1, off sc0 sc1\n\t"
                 "s_waitcnt vmcnt(0)"
                 : "=&v"(r) : "v"(a) : "memory");
    return r;
}

// 128 blocks x 512 threads, persistent. Wave w (0..7) of block b owns hidden
// unit u = 8b + w (gate rows u, 1024+u, 2048+u, 3072+u). Weights in VGPRs.
// Handoff: packed (epoch<<32 | f32) u64 per unit, 2-slot ring; thread tid
// polls the two contiguous slots 2tid, 2tid+1.
__global__ __launch_bounds__(NTHR, 2)
void lstm_persistent(const float* __restrict__ x,
                     const float* __restrict__ W_ih,
                     const float* __restrict__ W_hh,
                     const float* __restrict__ b_ih,
                     const float* __restrict__ b_hh,
                     const float* __restrict__ h0,
                     const float* __restrict__ c0,
                     float* __restrict__ out,
                     unsigned long long* __restrict__ ring)
{
    __shared__ float h_lds[2][HDIM];

    const int tid = threadIdx.x;
    const int w   = tid >> 6;   // wave 0..7
    const int l   = tid & 63;   // lane
    const int u   = (blockIdx.x << 3) + w;

    // register-resident weights: lane l covers elements 4l + 256i (+j)
    float4 Whh[4][4], Wih[4][4];
#pragma unroll
    for (int q = 0; q < 4; ++q) {
        const float* rh = W_hh + (size_t)(q * HDIM + u) * HDIM;
        const float* ri = W_ih + (size_t)(q * HDIM + u) * HDIM;
#pragma unroll
        for (int i = 0; i < 4; ++i) {
            Whh[q][i] = *(const float4*)(rh + 4 * l + 256 * i);
            Wih[q][i] = *(const float4*)(ri + 4 * l + 256 * i);
        }
    }
    float bias[4];
#pragma unroll
    for (int q = 0; q < 4; ++q) bias[q] = b_ih[q * HDIM + u] + b_hh[q * HDIM + u];
    float c = c0[u];  // replicated across the wave

    float4 hr[4];
#pragma unroll
    for (int i = 0; i < 4; ++i) hr[i] = *(const float4*)(h0 + 4 * l + 256 * i);

    // x pipeline: gxp = Wih-partials for step t (from x[t]); xr = x[t+1]
    float gxp[4];
    {
        float4 x0[4];
#pragma unroll
        for (int i = 0; i < 4; ++i) x0[i] = *(const float4*)(x + 4 * l + 256 * i);
#pragma unroll
        for (int q = 0; q < 4; ++q) {
            float a = 0.f;
#pragma unroll
            for (int i = 0; i < 4; ++i) a += dot4(Wih[q][i], x0[i]);
            gxp[q] = a;
        }
    }
    float4 xr[4], xn[4];
#pragma unroll
    for (int i = 0; i < 4; ++i) xr[i] = *(const float4*)(x + HDIM + 4 * l + 256 * i);

    for (int t = 0; t < T_STEPS; ++t) {
        // gates = gxp + Whh . h_{t-1}  (per-lane partials)
        float acc[4];
#pragma unroll
        for (int q = 0; q < 4; ++q) {
            float a = gxp[q];
#pragma unroll
            for (int i = 0; i < 4; ++i) a += dot4(Whh[q][i], hr[i]);
            acc[q] = a;
        }
#pragma unroll
        for (int m = 1; m < 64; m <<= 1) {
#pragma unroll
            for (int q = 0; q < 4; ++q) acc[q] += __shfl_xor(acc[q], m, 64);
        }
        const float gi = sigmoidf_(acc[0] + bias[0]);
        const float gf = sigmoidf_(acc[1] + bias[1]);
        const float gg = tanhf_   (acc[2] + bias[2]);
        const float go = sigmoidf_(acc[3] + bias[3]);
        c = gf * c + gi * gg;
        const float hval = go * tanhf_(c);

        if (l == 0) {
            const unsigned long long pk =
                ((unsigned long long)(unsigned)(t + 1) << 32) |
                (unsigned long long)__float_as_uint(hval);
            __hip_atomic_store(&ring[(t & 1) * HDIM + u], pk,
                               __ATOMIC_RELAXED, __HIP_MEMORY_SCOPE_AGENT);
            out[(size_t)t * HDIM + u] = hval;
        }
        if (t == T_STEPS - 1) break;

        // x[t+2] prefetch — issued before the poll so the poll's vmcnt(0)
        // absorbs its latency once, off the next iteration's critical path
        {
            const int tn = (t + 2 < T_STEPS) ? (t + 2) : (T_STEPS - 1);
            const float* xp = x + (size_t)tn * HDIM;
#pragma unroll
            for (int i = 0; i < 4; ++i) xn[i] = *(const float4*)(xp + 4 * l + 256 * i);
        }
        // gx partials for step t+1 (independent of h_t)
#pragma unroll
        for (int q = 0; q < 4; ++q) {
            float a = 0.f;
#pragma unroll
            for (int i = 0; i < 4; ++i) a += dot4(Wih[q][i], xr[i]);
            gxp[q] = a;
        }

        // wait for h_t: single 16B coherent load per poll iteration
        {
            const unsigned e = (unsigned)(t + 1);
            const unsigned long long base =
                (unsigned long long)(ring + (t & 1) * HDIM + 2 * tid);
            u32x4 p;
            for (;;) {
                p = poll2(base);
                if ((unsigned)p.y == e && (unsigned)p.w == e) break;
            }
            const int ns = (t + 1) & 1;
            h_lds[ns][2 * tid    ] = __uint_as_float((unsigned)p.x);
            h_lds[ns][2 * tid + 1] = __uint_as_float((unsigned)p.z);
        }
        __syncthreads();
        {
            const int ns = (t + 1) & 1;
#pragma unroll
            for (int i = 0; i < 4; ++i)
                hr[i] = *(const float4*)&h_lds[ns][4 * l + 256 * i];
        }
#pragma unroll
        for (int i = 0; i < 4; ++i) xr[i] = xn[i];
    }
}

extern "C" void kernel_launch(void* const* d_in, const int* in_sizes, int n_in,
                              void* d_out, int out_size, void* d_ws, size_t ws_size,
                              hipStream_t stream)
{
    const float* x    = (const float*)d_in[0];
    const float* W_ih = (const float*)d_in[1];
    const float* W_hh = (const float*)d_in[2];
    const float* b_ih = (const float*)d_in[3];
    const float* b_hh = (const float*)d_in[4];
    const float* h0   = (const float*)d_in[5];
    const float* c0   = (const float*)d_in[6];

    unsigned long long* ring = (unsigned long long*)d_ws;
    hipMemsetAsync(d_ws, 0, 2 * HDIM * sizeof(unsigned long long), stream);
    lstm_persistent<<<NBLK, NTHR, 0, stream>>>(x, W_ih, W_hh, b_ih, b_hh, h0, c0,
                                               (float*)d_out, ring);
}

// Round 3
// 23399.454 us; speedup vs baseline: 1.1036x; 1.1036x over previous
//
#include <hip/hip_runtime.h>
#include <cstdint>

#define T_STEPS 8192
#define HDIM    1024
#define NBLK    256
#define NTHR    256

typedef float        f32x4 __attribute__((ext_vector_type(4)));
typedef unsigned int u32x4 __attribute__((ext_vector_type(4)));

__device__ __forceinline__ float dot4(f32x4 a, f32x4 b) {
    return a[0] * b[0] + a[1] * b[1] + a[2] * b[2] + a[3] * b[3];
}
__device__ __forceinline__ float sigmoidf_(float v) { return 1.0f / (1.0f + __expf(-v)); }
__device__ __forceinline__ float tanhf_(float v)    { return 1.0f - 2.0f / (__expf(2.0f * v) + 1.0f); }

// 256 blocks x 256 threads (1 block/CU, 1 wave/SIMD -> VGPR cap ~512).
// Wave w (0..3) of block b owns hidden unit u = 4b + w (rows u, 1024+u,
// 2048+u, 3072+u of W_ih/W_hh). Weights are loaded ONCE and pinned into
// VGPRs with an asm barrier so the compiler cannot re-load them per step
// (R2's VGPR_Count=112 proved it was reloading 512B/thread/step).
// Handoff: packed (epoch<<32 | f32) u64 per unit, 2-slot ring in d_ws;
// thread tid polls its 4 contiguous slots (32B) with one asm block =
// two dwordx4 loads + one vmcnt(0) (single round-trip per poll).
__global__ __launch_bounds__(NTHR, 1)
void lstm_persistent(const float* __restrict__ x,
                     const float* __restrict__ W_ih,
                     const float* __restrict__ W_hh,
                     const float* __restrict__ b_ih,
                     const float* __restrict__ b_hh,
                     const float* __restrict__ h0,
                     const float* __restrict__ c0,
                     float* __restrict__ out,
                     unsigned long long* __restrict__ ring)
{
    __shared__ float h_lds[2][HDIM];

    const int tid = threadIdx.x;
    const int w   = tid >> 6;   // wave 0..3
    const int l   = tid & 63;   // lane
    const int u   = (blockIdx.x << 2) + w;

    // ---- load weights once: lane l covers elements 4l + 256i (+j) ----
    f32x4 whh[16], wih[16];
#pragma unroll
    for (int q = 0; q < 4; ++q) {
        const float* rh = W_hh + (size_t)(q * HDIM + u) * HDIM + 4 * l;
        const float* ri = W_ih + (size_t)(q * HDIM + u) * HDIM + 4 * l;
#pragma unroll
        for (int i = 0; i < 4; ++i) {
            whh[q * 4 + i] = *(const f32x4*)(rh + 256 * i);
            wih[q * 4 + i] = *(const f32x4*)(ri + 256 * i);
        }
    }
    // pin: values become asm-produced -> unrematerializable, must stay in VGPRs
#pragma unroll
    for (int k = 0; k < 16; ++k) {
        asm volatile("" : "+v"(whh[k]));
        asm volatile("" : "+v"(wih[k]));
    }

    float bias[4];
#pragma unroll
    for (int q = 0; q < 4; ++q) bias[q] = b_ih[q * HDIM + u] + b_hh[q * HDIM + u];
    float c = c0[u];  // replicated across the wave

    f32x4 hr[4];
#pragma unroll
    for (int i = 0; i < 4; ++i) hr[i] = *(const f32x4*)(h0 + 4 * l + 256 * i);

    // x pipeline: gxp = Wih partials for step t; xr = x[t+1]; xn = x[t+2]
    float gxp[4];
    {
        f32x4 x0[4];
#pragma unroll
        for (int i = 0; i < 4; ++i) x0[i] = *(const f32x4*)(x + 4 * l + 256 * i);
#pragma unroll
        for (int q = 0; q < 4; ++q) {
            float a = 0.f;
#pragma unroll
            for (int i = 0; i < 4; ++i) a += dot4(wih[q * 4 + i], x0[i]);
            gxp[q] = a;
        }
    }
    f32x4 xr[4], xn[4];
#pragma unroll
    for (int i = 0; i < 4; ++i) xr[i] = *(const f32x4*)(x + HDIM + 4 * l + 256 * i);

    for (int t = 0; t < T_STEPS; ++t) {
        // gates = gxp + Whh . h_{t-1}  (per-lane partials)
        float acc[4];
#pragma unroll
        for (int q = 0; q < 4; ++q) {
            float a = gxp[q];
#pragma unroll
            for (int i = 0; i < 4; ++i) a += dot4(whh[q * 4 + i], hr[i]);
            acc[q] = a;
        }
#pragma unroll
        for (int m = 1; m < 64; m <<= 1) {
#pragma unroll
            for (int q = 0; q < 4; ++q) acc[q] += __shfl_xor(acc[q], m, 64);
        }
        const float gi = sigmoidf_(acc[0] + bias[0]);
        const float gf = sigmoidf_(acc[1] + bias[1]);
        const float gg = tanhf_   (acc[2] + bias[2]);
        const float go = sigmoidf_(acc[3] + bias[3]);
        c = gf * c + gi * gg;
        const float hval = go * tanhf_(c);

        if (l == 0) {
            const unsigned long long pk =
                ((unsigned long long)(unsigned)(t + 1) << 32) |
                (unsigned long long)__float_as_uint(hval);
            __hip_atomic_store(&ring[(t & 1) * HDIM + u], pk,
                               __ATOMIC_RELAXED, __HIP_MEMORY_SCOPE_AGENT);
            out[(size_t)t * HDIM + u] = hval;
        }
        if (t == T_STEPS - 1) break;

        // x[t+2] prefetch (latency absorbed by the poll wait)
        {
            const int tn = (t + 2 < T_STEPS) ? (t + 2) : (T_STEPS - 1);
            const float* xp = x + (size_t)tn * HDIM;
#pragma unroll
            for (int i = 0; i < 4; ++i) xn[i] = *(const f32x4*)(xp + 4 * l + 256 * i);
        }
        // gx partials for step t+1 (independent of h_t)
#pragma unroll
        for (int q = 0; q < 4; ++q) {
            float a = 0.f;
#pragma unroll
            for (int i = 0; i < 4; ++i) a += dot4(wih[q * 4 + i], xr[i]);
            gxp[q] = a;
        }

        // wait for h_t: thread polls its 4 contiguous slots, one vmcnt per poll
        {
            const unsigned e = (unsigned)(t + 1);
            const unsigned long long base =
                (unsigned long long)(ring + (t & 1) * HDIM + 4 * tid);
            u32x4 p0, p1;
            for (;;) {
                asm volatile(
                    "global_load_dwordx4 %0, %2, off sc0 sc1\n\t"
                    "global_load_dwordx4 %1, %2, off offset:16 sc0 sc1\n\t"
                    "s_waitcnt vmcnt(0)"
                    : "=&v"(p0), "=&v"(p1)
                    : "v"(base)
                    : "memory");
                if (p0[1] == e && p0[3] == e && p1[1] == e && p1[3] == e) break;
            }
            const int ns = (t + 1) & 1;
            f32x4 hv;
            hv[0] = __uint_as_float(p0[0]);
            hv[1] = __uint_as_float(p0[2]);
            hv[2] = __uint_as_float(p1[0]);
            hv[3] = __uint_as_float(p1[2]);
            *(f32x4*)&h_lds[ns][4 * tid] = hv;
        }
        __syncthreads();
        {
            const int ns = (t + 1) & 1;
#pragma unroll
            for (int i = 0; i < 4; ++i)
                hr[i] = *(const f32x4*)&h_lds[ns][4 * l + 256 * i];
        }
#pragma unroll
        for (int i = 0; i < 4; ++i) xr[i] = xn[i];
    }
}

extern "C" void kernel_launch(void* const* d_in, const int* in_sizes, int n_in,
                              void* d_out, int out_size, void* d_ws, size_t ws_size,
                              hipStream_t stream)
{
    const float* x    = (const float*)d_in[0];
    const float* W_ih = (const float*)d_in[1];
    const float* W_hh = (const float*)d_in[2];
    const float* b_ih = (const float*)d_in[3];
    const float* b_hh = (const float*)d_in[4];
    const float* h0   = (const float*)d_in[5];
    const float* c0   = (const float*)d_in[6];

    unsigned long long* ring = (unsigned long long*)d_ws;
    hipMemsetAsync(d_ws, 0, 2 * HDIM * sizeof(unsigned long long), stream);
    lstm_persistent<<<NBLK, NTHR, 0, stream>>>(x, W_ih, W_hh, b_ih, b_hh, h0, c0,
                                               (float*)d_out, ring);
}